// Round 11
// baseline (134.569 us; speedup 1.0000x reference)
//
#include <hip/hip_runtime.h>
#include <math.h>

// Shapes (from setup_inputs): B=2, N=512, C=256, H=128, W=224.
#define PTS 8    // points per MLP block
#define PX 16    // pixels per tile
#define CH 8     // gaussians per weight chunk
#define NT 7     // tiles per half-row
#define HPX 112  // pixels per half-row

// ---------------- kernel 1: per-gaussian projection/prep ----------------
__global__ void prep_kernel(const float* __restrict__ gd,
                            const float* __restrict__ Kmat,
                            float4* __restrict__ bbox,
                            float4* __restrict__ prm,
                            int N, int B, float Wf, float Hf) {
  int i = blockIdx.x * blockDim.x + threadIdx.x;
  if (i >= B * N) return;
  int b = i / N;
  const float* g = gd + (size_t)i * 14;
  float X = g[0], Y = g[1], Z = g[2];
  float sigx = g[5], sigy = g[6], wt = g[12];
  const float* K = Kmat + (size_t)b * 9;
  float p0 = K[0]*X + K[1]*Y + K[2]*Z;
  float p1 = K[3]*X + K[4]*Y + K[5]*Z;
  float p2 = K[6]*X + K[7]*Y + K[8]*Z;
  float denom = p2 + 1e-6f;
  float p2x = p0 / denom, p2y = p1 / denom;
  float scale_x = Wf / K[2] * 0.5f;
  float scale_y = Hf / K[5] * 0.5f;
  float cx = p2x * scale_x;
  float cy = p2y * scale_y;
  bool valid = Z > 0.1f;
  bool inb = (cx >= 0.f) && (cx < Wf) && (cy >= 0.f) && (cy < Hf);
  bool active = valid && inb;
  float sxv = fmaxf(sigx * scale_x, 1.f);
  float syv = fmaxf(sigy * scale_y, 1.f);
  float wn = active ? wt : 0.f;
  float avg = 0.5f * (sxv + syv);
  if (active && wn != 0.f) {
    bbox[i] = make_float4(cx, cy, 3.f * sxv, 3.f * syv);
  } else {
    bbox[i] = make_float4(-1e30f, -1e30f, 0.f, 0.f);
  }
  prm[i] = make_float4(1.f / sxv, 1.f / syv, wn, avg);
}

// ---------------- kernel 2: MLP h = relu(pf@W1^T+b1)@W2^T+b2 ----------------
__global__ __launch_bounds__(256, 2) void mlp_kernel(
    const float* __restrict__ pf, const float* __restrict__ W1,
    const float* __restrict__ b1, const float* __restrict__ W2,
    const float* __restrict__ b2, float* __restrict__ hout, int npts) {
  const int t = threadIdx.x;
  const int p0 = blockIdx.x * PTS;
  __shared__ __align__(16) float xs[PTS][256];

  const float4* pf4 = (const float4*)(pf + (size_t)p0 * 256);
  float4* xs4 = (float4*)&xs[0][0];
  #pragma unroll
  for (int i = 0; i < PTS * 64 / 256; ++i) xs4[t + 256 * i] = pf4[t + 256 * i];
  __syncthreads();

  float acc[PTS];
  float bb1 = b1[t];
  #pragma unroll
  for (int p = 0; p < PTS; ++p) acc[p] = bb1;
  const float* w1r = W1 + (size_t)t * 256;
  for (int k = 0; k < 256; k += 4) {
    float4 w = *(const float4*)(w1r + k);
    #pragma unroll
    for (int p = 0; p < PTS; ++p) {
      float4 x = *(const float4*)(&xs[p][k]);
      acc[p] += w.x * x.x + w.y * x.y + w.z * x.z + w.w * x.w;
    }
  }
  __syncthreads();
  #pragma unroll
  for (int p = 0; p < PTS; ++p) xs[p][t] = fmaxf(acc[p], 0.f);
  __syncthreads();

  float acc2[PTS];
  float bb2 = b2[t];
  #pragma unroll
  for (int p = 0; p < PTS; ++p) acc2[p] = bb2;
  const float* w2r = W2 + (size_t)t * 256;
  for (int k = 0; k < 256; k += 4) {
    float4 w = *(const float4*)(w2r + k);
    #pragma unroll
    for (int p = 0; p < PTS; ++p) {
      float4 x = *(const float4*)(&xs[p][k]);
      acc2[p] += w.x * x.x + w.y * x.y + w.z * x.z + w.w * x.w;
    }
  }
  #pragma unroll
  for (int p = 0; p < PTS; ++p)
    if (p0 + p < npts) hout[((size_t)(p0 + p)) * 256 + t] = acc2[p];
}

// ---------------- kernel 2b: per-row y-cull ---------------------------------
__global__ __launch_bounds__(256) void rowcull_kernel(
    const float4* __restrict__ bbox, unsigned short* __restrict__ rowlist,
    int* __restrict__ rowcnt, int N, int H, int W) {
  const int t = threadIdx.x;
  const int row = blockIdx.x;
  const int b = blockIdx.y;
  __shared__ int wcnt[4];
  const float rf = (float)row;
  const float wmax = (float)(W - 1);
  const int lane = t & 63, wave = t >> 6;
  const unsigned long long lmask = (1ull << lane) - 1ull;
  const size_t bN = (size_t)b * N;
  unsigned short* rl = rowlist + ((size_t)b * H + row) * N;

  int listlen = 0;
  for (int gb = 0; gb < N; gb += 256) {
    int g = gb + t;
    bool f = false;
    if (g < N) {
      float4 bb = bbox[bN + g];
      f = (bb.y - bb.w <= rf) && (bb.y + bb.w >= rf) &&
          (bb.x + bb.z >= 0.f) && (bb.x - bb.z <= wmax);
    }
    unsigned long long m = __ballot(f);
    if (lane == 0) wcnt[wave] = __popcll(m);
    __syncthreads();
    int pre = 0;
    #pragma unroll
    for (int wv = 0; wv < 4; ++wv) pre += (wv < wave) ? wcnt[wv] : 0;
    int tot = wcnt[0] + wcnt[1] + wcnt[2] + wcnt[3];
    if (f) rl[listlen + pre + __popcll(m & lmask)] = (unsigned short)g;
    __syncthreads();
    listlen += tot;
  }
  if (t == 0) rowcnt[(size_t)b * H + row] = listlen;
}

// ---------------- kernel 3: half-row splat (512 fat blocks) -----------------
// block = (half, row, b): 7 tiles of 16 px x 256 ch. Row params staged in LDS
// once; tile lists built in-LDS (no ballots, no global round-trip); 8-g
// double-buffered chunk engine per tile; stores spread across 7 tile-ends.
// Attacks the round-6..10 invariant: 7168 short blocks with end-bunched
// stores cost ~1.9us each regardless of content.
__global__ __launch_bounds__(256) void splatrow_kernel(
    const float4* __restrict__ bbox, const float4* __restrict__ prm,
    const float* __restrict__ hfeat,
    const unsigned short* __restrict__ rowlist, const int* __restrict__ rowcnt,
    float* __restrict__ fout, float* __restrict__ unc_out,
    float* __restrict__ dens_out, int N, int C, int H, int W) {
  const int t = threadIdx.x;
  const int b = blockIdx.z;
  const int row = blockIdx.y;
  const int half = blockIdx.x;
  const int HW = H * W;

  __shared__ __align__(16) float4 A_s[512];   // cx, 1/sx, w, avg
  __shared__ __align__(16) float4 B_s[512];   // dy2, xlo, xhi, g(bits)
  __shared__ unsigned int tl[NT][512];        // (g<<16) | rowlist-index
  __shared__ int tcnt[NT];
  __shared__ __align__(16) float wlds[2][CH][PX];
  __shared__ float avgs_s[2][CH];
  __shared__ __align__(16) float invd_s[PX];

  const float rf = (float)row;
  const size_t bN = (size_t)b * N;
  const int rcnt = rowcnt[(size_t)b * H + row];
  const unsigned short* rl = rowlist + ((size_t)b * H + row) * N;

  // ---- stage row params in LDS (parallel) ----
  for (int i = t; i < rcnt; i += 256) {
    int g = rl[i];
    float4 bb = bbox[bN + g];
    float4 pr = prm[bN + g];
    float dy = (rf - bb.y) * pr.y;
    A_s[i] = make_float4(bb.x, pr.x, pr.z, pr.w);
    B_s[i] = make_float4(dy * dy, bb.x - bb.z, bb.x + bb.z, __int_as_float(g));
  }
  __syncthreads();

  // ---- build 7 tile lists (ascending order preserved) ----
  if (t < NT) {
    const float txlo = (float)(half * HPX + t * PX);
    const float txhi = txlo + (float)(PX - 1);
    int c = 0;
    for (int i = 0; i < rcnt; ++i) {
      float4 Bv = B_s[i];
      if (Bv.z >= txlo && Bv.y <= txhi)
        tl[t][c++] = ((unsigned int)__float_as_int(Bv.w) << 16) | (unsigned int)i;
    }
    tcnt[t] = c;
  }
  __syncthreads();

  const int cg = t >> 2, pq = t & 3;      // 64 ch-quads x 4 px-quads
  const int gi_w = t >> 4, j_w = t & 15;  // weight slots (t<128)

#define HV8(HV, CB) do { \
    int gn_ = cnt - (CB); \
    _Pragma("unroll") \
    for (int gi = 0; gi < CH; ++gi) { \
      float4 hv_ = make_float4(0.f, 0.f, 0.f, 0.f); \
      if (gi < gn_) { \
        unsigned int pk_ = tl[tx][(CB) + gi]; \
        hv_ = *(const float4*)(hfeat + (bN + (pk_ >> 16)) * (size_t)C + 4 * cg); \
      } \
      HV[gi] = hv_; \
    } } while (0)

#define WGT8(BUF, CB) do { \
    if (t < CH * PX) { \
      float w_ = 0.f, av_ = 0.f; \
      int gn_ = cnt - (CB); \
      if (gi_w < gn_) { \
        int i_ = (int)(tl[tx][(CB) + gi_w] & 0xffffu); \
        float4 A_ = A_s[i_]; \
        float dx_ = ((float)(x0 + j_w) - A_.x) * A_.y; \
        float q_ = dx_ * dx_ + B_s[i_].x; \
        w_ = (q_ < 9.f) ? __expf(-0.5f * q_) * A_.z : 0.f; \
        av_ = A_.w; \
      } \
      wlds[BUF][gi_w][j_w] = w_; \
      if (j_w == 0) avgs_s[BUF][gi_w] = av_; \
    } } while (0)

#define DENS8(BUF, GC) do { \
    if (t < PX) { \
      for (int gi = 0; gi < (GC); ++gi) { \
        float w = wlds[BUF][gi][t]; \
        dreg += w; ureg += w * avgs_s[BUF][gi]; \
      } } } while (0)

#define FMA8(BUF, HV) do { \
    const float4* wr_ = (const float4*)&wlds[BUF][0][0]; \
    _Pragma("unroll") \
    for (int gi = 0; gi < CH; ++gi) { \
      float4 w = wr_[gi * 4 + pq]; \
      float4 h = HV[gi]; \
      a0.x += w.x*h.x; a0.y += w.y*h.x; a0.z += w.z*h.x; a0.w += w.w*h.x; \
      a1.x += w.x*h.y; a1.y += w.y*h.y; a1.z += w.z*h.y; a1.w += w.w*h.y; \
      a2.x += w.x*h.z; a2.y += w.y*h.z; a2.z += w.z*h.z; a2.w += w.w*h.z; \
      a3.x += w.x*h.w; a3.y += w.y*h.w; a3.z += w.z*h.w; a3.w += w.w*h.w; \
    } } while (0)

  for (int tx = 0; tx < NT; ++tx) {
    const int x0 = half * HPX + tx * PX;
    const int cnt = tcnt[tx];
    const int nchunk = (cnt + CH - 1) / CH;

    float dreg = 0.f, ureg = 0.f;
    float4 a0 = make_float4(0.f, 0.f, 0.f, 0.f), a1 = a0, a2 = a0, a3 = a0;
    float4 hvA[CH], hvB[CH];

    if (nchunk > 0) {
      HV8(hvA, 0);
      WGT8(0, 0);
      __syncthreads();
      for (int c = 0; c < nchunk; c += 2) {
        {
          const int gc = min(CH, cnt - c * CH);
          HV8(hvB, (c + 1) * CH);
          WGT8(1, (c + 1) * CH);
          DENS8(0, gc);
          FMA8(0, hvA);
          __syncthreads();
        }
        if (c + 1 < nchunk) {
          const int gc = min(CH, cnt - (c + 1) * CH);
          HV8(hvA, (c + 2) * CH);
          WGT8(0, (c + 2) * CH);
          DENS8(1, gc);
          FMA8(1, hvB);
          __syncthreads();
        }
      }
    }

    if (t < PX) {
      float dc = fmaxf(dreg, 1e-6f);
      float inv = 1.f / dc;
      invd_s[t] = inv;
      size_t pix = (size_t)b * HW + (size_t)row * W + x0 + t;
      dens_out[pix] = dc;
      unc_out[pix] = ureg * inv;
    }
    __syncthreads();

    float4 iq = *(const float4*)&invd_s[4 * pq];
    float* fo = fout + ((size_t)(b * C + 4 * cg)) * HW + (size_t)row * W + x0 + 4 * pq;
    *(float4*)(fo)        = make_float4(a0.x*iq.x, a0.y*iq.y, a0.z*iq.z, a0.w*iq.w);
    *(float4*)(fo + HW)   = make_float4(a1.x*iq.x, a1.y*iq.y, a1.z*iq.z, a1.w*iq.w);
    *(float4*)(fo + 2*HW) = make_float4(a2.x*iq.x, a2.y*iq.y, a2.z*iq.z, a2.w*iq.w);
    *(float4*)(fo + 3*HW) = make_float4(a3.x*iq.x, a3.y*iq.y, a3.z*iq.z, a3.w*iq.w);
    __syncthreads();   // protect invd_s / wlds before next tile
  }

#undef HV8
#undef WGT8
#undef DENS8
#undef FMA8
}

extern "C" void kernel_launch(void* const* d_in, const int* in_sizes, int n_in,
                              void* d_out, int out_size, void* d_ws, size_t ws_size,
                              hipStream_t stream) {
  const float* pf = (const float*)d_in[0];
  const float* gd = (const float*)d_in[1];
  const float* K  = (const float*)d_in[2];
  const float* W1 = (const float*)d_in[3];
  const float* b1 = (const float*)d_in[4];
  const float* W2 = (const float*)d_in[5];
  const float* b2 = (const float*)d_in[6];

  const int B = in_sizes[2] / 9;
  const int N = in_sizes[1] / (B * 14);
  const int C = in_sizes[0] / (B * N);
  const int H = 128, W = 224;

  char* wsb = (char*)d_ws;
  size_t off = 0;
  float4* bbox = (float4*)(wsb + off); off += (size_t)B * N * sizeof(float4);
  float4* prm  = (float4*)(wsb + off); off += (size_t)B * N * sizeof(float4);
  float*  hfe  = (float*)(wsb + off);  off += (size_t)B * N * C * 4;
  unsigned short* rowlist = (unsigned short*)(wsb + off);
  off += (size_t)B * H * N * 2;
  off = (off + 15) & ~(size_t)15;
  int* rowcnt = (int*)(wsb + off);

  float* out      = (float*)d_out;
  float* unc_out  = out + (size_t)B * C * H * W;
  float* dens_out = unc_out + (size_t)B * H * W;

  prep_kernel<<<dim3((B * N + 255) / 256), 256, 0, stream>>>(
      gd, K, bbox, prm, N, B, (float)W, (float)H);
  rowcull_kernel<<<dim3(H, B), 256, 0, stream>>>(
      bbox, rowlist, rowcnt, N, H, W);
  mlp_kernel<<<dim3((B * N + PTS - 1) / PTS), 256, 0, stream>>>(
      pf, W1, b1, W2, b2, hfe, B * N);
  splatrow_kernel<<<dim3(2, H, B), 256, 0, stream>>>(
      bbox, prm, hfe, rowlist, rowcnt, out, unc_out, dens_out, N, C, H, W);
}

// Round 12
// 89.029 us; speedup vs baseline: 1.5115x; 1.5115x over previous
//
#include <hip/hip_runtime.h>
#include <math.h>

// Shapes (from setup_inputs): B=2, N=512, C=256, H=128, W=224.
#define PTS 8    // points per MLP block
#define PX 16    // pixels per tile
#define CH 8     // gaussians per weight chunk
#define NTX 14   // tiles per row (W/PX)
#define NBLK 1536 // persistent splat blocks (6/CU at VGPR~80)

// ---------------- kernel 1: per-gaussian projection/prep ----------------
__global__ void prep_kernel(const float* __restrict__ gd,
                            const float* __restrict__ Kmat,
                            float4* __restrict__ bbox,
                            float4* __restrict__ prm,
                            int N, int B, float Wf, float Hf) {
  int i = blockIdx.x * blockDim.x + threadIdx.x;
  if (i >= B * N) return;
  int b = i / N;
  const float* g = gd + (size_t)i * 14;
  float X = g[0], Y = g[1], Z = g[2];
  float sigx = g[5], sigy = g[6], wt = g[12];
  const float* K = Kmat + (size_t)b * 9;
  float p0 = K[0]*X + K[1]*Y + K[2]*Z;
  float p1 = K[3]*X + K[4]*Y + K[5]*Z;
  float p2 = K[6]*X + K[7]*Y + K[8]*Z;
  float denom = p2 + 1e-6f;
  float p2x = p0 / denom, p2y = p1 / denom;
  float scale_x = Wf / K[2] * 0.5f;
  float scale_y = Hf / K[5] * 0.5f;
  float cx = p2x * scale_x;
  float cy = p2y * scale_y;
  bool valid = Z > 0.1f;
  bool inb = (cx >= 0.f) && (cx < Wf) && (cy >= 0.f) && (cy < Hf);
  bool active = valid && inb;
  float sxv = fmaxf(sigx * scale_x, 1.f);
  float syv = fmaxf(sigy * scale_y, 1.f);
  float wn = active ? wt : 0.f;
  float avg = 0.5f * (sxv + syv);
  if (active && wn != 0.f) {
    bbox[i] = make_float4(cx, cy, 3.f * sxv, 3.f * syv);
  } else {
    bbox[i] = make_float4(-1e30f, -1e30f, 0.f, 0.f);
  }
  prm[i] = make_float4(1.f / sxv, 1.f / syv, wn, avg);
}

// ---------------- kernel 2: MLP h = relu(pf@W1^T+b1)@W2^T+b2 ----------------
__global__ __launch_bounds__(256, 2) void mlp_kernel(
    const float* __restrict__ pf, const float* __restrict__ W1,
    const float* __restrict__ b1, const float* __restrict__ W2,
    const float* __restrict__ b2, float* __restrict__ hout, int npts) {
  const int t = threadIdx.x;
  const int p0 = blockIdx.x * PTS;
  __shared__ __align__(16) float xs[PTS][256];

  const float4* pf4 = (const float4*)(pf + (size_t)p0 * 256);
  float4* xs4 = (float4*)&xs[0][0];
  #pragma unroll
  for (int i = 0; i < PTS * 64 / 256; ++i) xs4[t + 256 * i] = pf4[t + 256 * i];
  __syncthreads();

  float acc[PTS];
  float bb1 = b1[t];
  #pragma unroll
  for (int p = 0; p < PTS; ++p) acc[p] = bb1;
  const float* w1r = W1 + (size_t)t * 256;
  for (int k = 0; k < 256; k += 4) {
    float4 w = *(const float4*)(w1r + k);
    #pragma unroll
    for (int p = 0; p < PTS; ++p) {
      float4 x = *(const float4*)(&xs[p][k]);
      acc[p] += w.x * x.x + w.y * x.y + w.z * x.z + w.w * x.w;
    }
  }
  __syncthreads();
  #pragma unroll
  for (int p = 0; p < PTS; ++p) xs[p][t] = fmaxf(acc[p], 0.f);
  __syncthreads();

  float acc2[PTS];
  float bb2 = b2[t];
  #pragma unroll
  for (int p = 0; p < PTS; ++p) acc2[p] = bb2;
  const float* w2r = W2 + (size_t)t * 256;
  for (int k = 0; k < 256; k += 4) {
    float4 w = *(const float4*)(w2r + k);
    #pragma unroll
    for (int p = 0; p < PTS; ++p) {
      float4 x = *(const float4*)(&xs[p][k]);
      acc2[p] += w.x * x.x + w.y * x.y + w.z * x.z + w.w * x.w;
    }
  }
  #pragma unroll
  for (int p = 0; p < PTS; ++p)
    if (p0 + p < npts) hout[((size_t)(p0 + p)) * 256 + t] = acc2[p];
}

// ---------------- kernel 2b: fused row+tile cull (fully parallel) -----------
// block = (row, b). Phase 1: 256-thread ballot row-cull into LDS (ascending).
// Phase 2: each WAVE handles tiles wave, wave+4, ... with 64-lane ballots over
// the LDS row list (no serial scans — round-8/11's mistake). Lists to global.
__global__ __launch_bounds__(256) void tilecull_kernel(
    const float4* __restrict__ bbox, int* __restrict__ tilelist,
    int* __restrict__ tilecnt, int N, int H, int W) {
  const int t = threadIdx.x;
  const int row = blockIdx.x;
  const int b = blockIdx.y;
  __shared__ int wcnt[4];
  __shared__ float xlo_s[512], xhi_s[512];
  __shared__ short gid_s[512];
  const float rf = (float)row;
  const float wmax = (float)(W - 1);
  const int lane = t & 63, wave = t >> 6;
  const unsigned long long lmask = (1ull << lane) - 1ull;
  const size_t bN = (size_t)b * N;

  // phase 1: row cull (ascending g)
  int rowlen = 0;
  for (int gb = 0; gb < N; gb += 256) {
    int g = gb + t;
    bool f = false;
    float bxlo = 0.f, bxhi = 0.f;
    if (g < N) {
      float4 bb = bbox[bN + g];
      bxlo = bb.x - bb.z; bxhi = bb.x + bb.z;
      f = (bb.y - bb.w <= rf) && (bb.y + bb.w >= rf) &&
          (bxhi >= 0.f) && (bxlo <= wmax);
    }
    unsigned long long m = __ballot(f);
    if (lane == 0) wcnt[wave] = __popcll(m);
    __syncthreads();
    int pre = 0;
    #pragma unroll
    for (int wv = 0; wv < 4; ++wv) pre += (wv < wave) ? wcnt[wv] : 0;
    int tot = wcnt[0] + wcnt[1] + wcnt[2] + wcnt[3];
    if (f) {
      int idx = rowlen + pre + __popcll(m & lmask);
      gid_s[idx] = (short)g; xlo_s[idx] = bxlo; xhi_s[idx] = bxhi;
    }
    __syncthreads();
    rowlen += tot;
  }

  // phase 2: wave-per-tile x-cull from LDS (ascending preserved)
  for (int tx = wave; tx < NTX; tx += 4) {
    const float txlo = (float)(tx * PX), txhi = txlo + (float)(PX - 1);
    const size_t tid = ((size_t)b * H + row) * NTX + tx;
    int* out = tilelist + tid * 512;
    int cnt = 0;
    for (int rb = 0; rb < rowlen; rb += 64) {
      int i = rb + lane;
      bool f = false; int g = 0;
      if (i < rowlen) {
        f = (xhi_s[i] >= txlo) && (xlo_s[i] <= txhi);
        g = gid_s[i];
      }
      unsigned long long m = __ballot(f);
      if (f) out[cnt + __popcll(m & lmask)] = g;
      cnt += __popcll(m);
    }
    if (lane == 0) tilecnt[tid] = cnt;
  }
}

// ---------------- kernel 3: PERSISTENT gather-splat -------------------------
// 1536 blocks (6/CU) grid-stride over 7168 tiles: 6 independent blocks per CU
// resident by construction (rounds 6-10: 7168 short blocks ran ~back-to-back,
// cull-only ablation = 15us for no work). Per-tile prologue = cnt + list load;
// cnt==0 fast path; round-10 chunk engine (CH=8, double-buffered, prefetch at
// chunk top) kept verbatim.
__global__ __launch_bounds__(256) void splat_kernel(
    const float4* __restrict__ bbox, const float4* __restrict__ prm,
    const float* __restrict__ hfeat,
    const int* __restrict__ tilelist, const int* __restrict__ tilecnt,
    float* __restrict__ fout, float* __restrict__ unc_out,
    float* __restrict__ dens_out, int N, int C, int H, int W, int ntiles) {
  const int t = threadIdx.x;
  const int HW = H * W;

  __shared__ int glist[512];
  __shared__ __align__(16) float wlds[2][CH][PX];
  __shared__ __align__(16) float invd_s[PX];
  __shared__ float avgs_s[2][CH];

  const int cg = t >> 2, pq = t & 3;      // 64 ch-quads x 4 px-quads
  const int gi_w = t >> 4, j_w = t & 15;  // weight slots (t<128)

  for (int tid = blockIdx.x; tid < ntiles; tid += NBLK) {
    const int tx = tid % NTX;
    const int rowb = tid / NTX;
    const int row = rowb % H;
    const int b = rowb / H;
    const int x0 = tx * PX;
    const size_t bN = (size_t)b * N;
    const float rf = (float)row;
    const float xlo = (float)x0;

    const int cnt = tilecnt[tid];
    __syncthreads();   // previous tile fully done with glist/wlds/invd_s

    // ---------- fast path: empty tile ----------
    if (cnt == 0) {
      if (t < PX) {
        size_t pix = (size_t)b * HW + (size_t)row * W + x0 + t;
        dens_out[pix] = 1e-6f;
        unc_out[pix] = 0.f;
      }
      float4 z = make_float4(0.f, 0.f, 0.f, 0.f);
      float* fo = fout + ((size_t)(b * C + 4 * cg)) * HW + (size_t)row * W + x0 + 4 * pq;
      *(float4*)(fo)        = z;
      *(float4*)(fo + HW)   = z;
      *(float4*)(fo + 2*HW) = z;
      *(float4*)(fo + 3*HW) = z;
      continue;
    }

    for (int i = t; i < cnt; i += 256) glist[i] = tilelist[(size_t)tid * 512 + i];
    __syncthreads();

    float dreg = 0.f, ureg = 0.f;
    float4 a0 = make_float4(0.f,0.f,0.f,0.f), a1 = a0, a2 = a0, a3 = a0;
    float4 hvA[CH], hvB[CH];
    const int nchunk = (cnt + CH - 1) / CH;

#define HV8(HV, CB) do { \
    int gn_ = cnt - (CB); \
    _Pragma("unroll") \
    for (int gi = 0; gi < CH; ++gi) { \
      int idx_ = (CB) + gi; if (idx_ > cnt - 1) idx_ = cnt - 1; \
      HV[gi] = (gi < gn_) ? *(const float4*)(hfeat + (bN + glist[idx_]) * (size_t)C + 4 * cg) \
                          : make_float4(0.f, 0.f, 0.f, 0.f); \
    } } while (0)

#define WGT8(BUF, CB) do { \
    if (t < CH * PX) { \
      float w_ = 0.f, av_ = 0.f; \
      int gn_ = cnt - (CB); \
      if (gi_w < gn_) { \
        int g_ = glist[(CB) + gi_w]; \
        float4 bb_ = bbox[bN + g_]; \
        float4 pr_ = prm[bN + g_]; \
        float dx_ = (xlo + (float)j_w - bb_.x) * pr_.x; \
        float dy_ = (rf - bb_.y) * pr_.y; \
        float q_ = dx_ * dx_ + dy_ * dy_; \
        w_ = (q_ < 9.f) ? __expf(-0.5f * q_) * pr_.z : 0.f; \
        av_ = pr_.w; \
      } \
      wlds[BUF][gi_w][j_w] = w_; \
      if (j_w == 0) avgs_s[BUF][gi_w] = av_; \
    } } while (0)

#define DENS8(BUF, GC) do { \
    if (t < PX) { \
      for (int gi = 0; gi < (GC); ++gi) { \
        float w = wlds[BUF][gi][t]; \
        dreg += w; ureg += w * avgs_s[BUF][gi]; \
      } } } while (0)

#define FMA8(BUF, HV) do { \
    const float4* wr_ = (const float4*)&wlds[BUF][0][0]; \
    _Pragma("unroll") \
    for (int gi = 0; gi < CH; ++gi) { \
      float4 w = wr_[gi * 4 + pq]; \
      float4 h = HV[gi]; \
      a0.x += w.x*h.x; a0.y += w.y*h.x; a0.z += w.z*h.x; a0.w += w.w*h.x; \
      a1.x += w.x*h.y; a1.y += w.y*h.y; a1.z += w.z*h.y; a1.w += w.w*h.y; \
      a2.x += w.x*h.z; a2.y += w.y*h.z; a2.z += w.z*h.z; a2.w += w.w*h.z; \
      a3.x += w.x*h.w; a3.y += w.y*h.w; a3.z += w.z*h.w; a3.w += w.w*h.w; \
    } } while (0)

    HV8(hvA, 0);
    WGT8(0, 0);
    __syncthreads();
    for (int c = 0; c < nchunk; c += 2) {
      {
        const int gc = min(CH, cnt - c * CH);
        HV8(hvB, (c + 1) * CH);
        WGT8(1, (c + 1) * CH);
        DENS8(0, gc);
        FMA8(0, hvA);
        __syncthreads();
      }
      if (c + 1 < nchunk) {
        const int gc = min(CH, cnt - (c + 1) * CH);
        HV8(hvA, (c + 2) * CH);
        WGT8(0, (c + 2) * CH);
        DENS8(1, gc);
        FMA8(1, hvB);
        __syncthreads();
      }
    }

    if (t < PX) {
      float dc = fmaxf(dreg, 1e-6f);
      float inv = 1.f / dc;
      invd_s[t] = inv;
      size_t pix = (size_t)b * HW + (size_t)row * W + x0 + t;
      dens_out[pix] = dc;
      unc_out[pix] = ureg * inv;
    }
    __syncthreads();

    float4 iq = *(const float4*)&invd_s[4 * pq];
    float* fo = fout + ((size_t)(b * C + 4 * cg)) * HW + (size_t)row * W + x0 + 4 * pq;
    *(float4*)(fo)        = make_float4(a0.x*iq.x, a0.y*iq.y, a0.z*iq.z, a0.w*iq.w);
    *(float4*)(fo + HW)   = make_float4(a1.x*iq.x, a1.y*iq.y, a1.z*iq.z, a1.w*iq.w);
    *(float4*)(fo + 2*HW) = make_float4(a2.x*iq.x, a2.y*iq.y, a2.z*iq.z, a2.w*iq.w);
    *(float4*)(fo + 3*HW) = make_float4(a3.x*iq.x, a3.y*iq.y, a3.z*iq.z, a3.w*iq.w);

#undef HV8
#undef WGT8
#undef DENS8
#undef FMA8
  }
}

extern "C" void kernel_launch(void* const* d_in, const int* in_sizes, int n_in,
                              void* d_out, int out_size, void* d_ws, size_t ws_size,
                              hipStream_t stream) {
  const float* pf = (const float*)d_in[0];
  const float* gd = (const float*)d_in[1];
  const float* K  = (const float*)d_in[2];
  const float* W1 = (const float*)d_in[3];
  const float* b1 = (const float*)d_in[4];
  const float* W2 = (const float*)d_in[5];
  const float* b2 = (const float*)d_in[6];

  const int B = in_sizes[2] / 9;
  const int N = in_sizes[1] / (B * 14);
  const int C = in_sizes[0] / (B * N);
  const int H = 128, W = 224;
  const int ntiles = B * H * NTX;

  char* wsb = (char*)d_ws;
  size_t off = 0;
  float4* bbox = (float4*)(wsb + off); off += (size_t)B * N * sizeof(float4);
  float4* prm  = (float4*)(wsb + off); off += (size_t)B * N * sizeof(float4);
  float*  hfe  = (float*)(wsb + off);  off += (size_t)B * N * C * 4;
  int* tilelist = (int*)(wsb + off);   off += (size_t)ntiles * 512 * 4;
  int* tilecnt  = (int*)(wsb + off);   off += (size_t)ntiles * 4;

  float* out      = (float*)d_out;
  float* unc_out  = out + (size_t)B * C * H * W;
  float* dens_out = unc_out + (size_t)B * H * W;

  prep_kernel<<<dim3((B * N + 255) / 256), 256, 0, stream>>>(
      gd, K, bbox, prm, N, B, (float)W, (float)H);
  tilecull_kernel<<<dim3(H, B), 256, 0, stream>>>(
      bbox, tilelist, tilecnt, N, H, W);
  mlp_kernel<<<dim3((B * N + PTS - 1) / PTS), 256, 0, stream>>>(
      pf, W1, b1, W2, b2, hfe, B * N);
  splat_kernel<<<dim3(NBLK), 256, 0, stream>>>(
      bbox, prm, hfe, tilelist, tilecnt, out, unc_out, dens_out,
      N, C, H, W, ntiles);
}